// Round 5
// baseline (7675.129 us; speedup 1.0000x reference)
//
#include <hip/hip_runtime.h>

// AdEx Euler integration, bit-faithful fp32 port of the jax/numpy reference.
// Sequential scan over T=40000 steps; N=1024 neurons. Wall time floor is the
// per-step dependent chain of a single wave; with one chain per lane the wave
// cannot overlap issue (~105 cyc/step) with chain latency (~130 cyc/step):
// measured 240 cyc/step ~= their SUM.
//
// R1: batched uniform I_ext scalar loads, double-buffered    8217 -> 7055 us
// R2: IEEE divs -> fp64 reciprocal-mul (Markstein, bit-exact) 7055 -> 4193 us
// R3: burst-store output buffering (store-WAR stalls)         4193 -> 4007 us
// R4: TWO neurons per lane (512 lanes, 8 waves): two independent chains
//     interleave in the issue stream, chain-B fills chain-A's bubbles.
//     Per-neuron math untouched -> absmax must stay exactly 4.882812e-04.
//     N templated (1024) so the pair store folds into the 13-bit imm offset.

__device__ __forceinline__ float fdiv_via_f64(float x, double inv_y) {
    // Markstein: f64 multiply by correctly-rounded f64 reciprocal rounds
    // identically to IEEE f32 division for all normal inputs (needs 2p+2=50
    // bits; f64 has 53). Bit-exact replacement, ~3 instrs vs ~10.
    return (float)((double)x * inv_y);
}

__device__ __forceinline__ void adex_step(
    float& V, float& w, float RI,
    float V_rest, float V_reset, float V_T, float V_thres,
    float delta_T, float R, float a, float b_over_dt, float dt,
    double inv_delta_T, double inv_tau, double inv_tau_w, double inv_dt)
{
#pragma clang fp contract(off)
    float t1   = V - V_rest;
    float ex   = expf(fdiv_via_f64(V - V_T, inv_delta_T));
    float s    = (-t1) + (delta_T * ex);
    s          = s - (R * w);
    s          = s + RI;
    float dvdt = fdiv_via_f64(s, inv_tau);
    float tw   = (a * t1) - w;
    float dwdt = fdiv_via_f64(tw, inv_tau_w);
    bool  spike  = V > V_thres;
    float dvdt_s = fdiv_via_f64(V_reset - V, inv_dt);
    dvdt = spike ? dvdt_s : dvdt;
    dwdt = spike ? (dwdt + b_over_dt) : dwdt;
    V = V + (dt * dvdt);
    w = w + (dt * dwdt);
}

template<int NC>
__global__ void __launch_bounds__(64, 1) adex_kernel(
    const float* __restrict__ I_ext,
    const float* __restrict__ V0,
    const float* __restrict__ w0,
    const float* __restrict__ p_V_rest,
    const float* __restrict__ p_V_reset,
    const float* __restrict__ p_V_T,
    const float* __restrict__ p_V_thres,
    const float* __restrict__ p_delta_T,
    const float* __restrict__ p_R,
    const float* __restrict__ p_tau,
    const float* __restrict__ p_tau_w,
    const float* __restrict__ p_a,
    const float* __restrict__ p_b,
    float* __restrict__ out,
    int T, int N_rt)
{
#pragma clang fp contract(off)
    const int N    = (NC > 0) ? NC : N_rt;
    const int half = N / 2;

    int lane = blockIdx.x * blockDim.x + threadIdx.x;
    if (lane >= half) lane = half - 1;   // uniform control flow (scalar I
                                         // loads); duplicate writes benign.
    const int n0 = lane;
    const int n1 = lane + half;

    const float dt      = 5e-5f;
    const float V_rest  = *p_V_rest;
    const float V_reset = *p_V_reset;
    const float V_T     = *p_V_T;
    const float V_thres = *p_V_thres;
    const float delta_T = *p_delta_T;
    const float R       = *p_R;
    const float tau     = *p_tau;
    const float tau_w   = *p_tau_w;
    const float a       = *p_a;
    const float b       = *p_b;
    const float b_over_dt = b / dt;   // off-loop, bit-identical hoist

    const double inv_delta_T = 1.0 / (double)delta_T;
    const double inv_tau     = 1.0 / (double)tau;
    const double inv_tau_w   = 1.0 / (double)tau_w;
    const double inv_dt      = 1.0 / (double)dt;

    float Va = V0[n0], wa = w0[n0];
    float Vb = V0[n1], wb = w0[n1];

    float* outV = out + n0;
    float* outW = out + (size_t)T * N + n0;

    // Double-buffered uniform I batches (R*I precomputed, off-chain).
    // I_ext has T+5 elements; prefetch base clamped so max index <= T+4.
    float A[8], B[8];
    float oVa[8], owa[8], oVb[8], owb[8];
#pragma unroll
    for (int j = 0; j < 8; ++j) A[j] = R * I_ext[j];

#define ADEX_PAIR(j, RI)                                                   \
    {                                                                      \
        oVa[j] = Va; owa[j] = wa; oVb[j] = Vb; owb[j] = wb;                \
        adex_step(Va, wa, (RI), V_rest, V_reset, V_T, V_thres, delta_T,    \
                  R, a, b_over_dt, dt, inv_delta_T, inv_tau, inv_tau_w,    \
                  inv_dt);                                                 \
        adex_step(Vb, wb, (RI), V_rest, V_reset, V_T, V_thres, delta_T,    \
                  R, a, b_over_dt, dt, inv_delta_T, inv_tau, inv_tau_w,    \
                  inv_dt);                                                 \
    }

#define ADEX_FLUSH()                                                       \
    {                                                                      \
        _Pragma("unroll")                                                  \
        for (int j = 0; j < 8; ++j) {                                      \
            outV[(size_t)j * N]        = oVa[j];                           \
            outV[(size_t)j * N + half] = oVb[j];                           \
            outW[(size_t)j * N]        = owa[j];                           \
            outW[(size_t)j * N + half] = owb[j];                           \
        }                                                                  \
        outV += (size_t)8 * N;                                             \
        outW += (size_t)8 * N;                                             \
    }

    for (int kb = 0; kb < T; kb += 16) {
        // prefetch B = I[kb+8 .. kb+15]  (kb <= T-16 -> max idx T-1, ok)
#pragma unroll
        for (int j = 0; j < 8; ++j) B[j] = R * I_ext[kb + 8 + j];

#pragma unroll
        for (int j = 0; j < 8; ++j) ADEX_PAIR(j, A[j]);
        ADEX_FLUSH();

        // prefetch A = I[kb+16 .. kb+23], clamped (pb+7 <= T+4); clamp only
        // triggers on the final iteration where the batch is unused.
        {
            int pb = kb + 16;
            if (pb > T - 3) pb = T - 3;
#pragma unroll
            for (int j = 0; j < 8; ++j) A[j] = R * I_ext[pb + j];
        }

#pragma unroll
        for (int j = 0; j < 8; ++j) ADEX_PAIR(j, B[j]);
        ADEX_FLUSH();
    }
#undef ADEX_PAIR
#undef ADEX_FLUSH
}

extern "C" void kernel_launch(void* const* d_in, const int* in_sizes, int n_in,
                              void* d_out, int out_size, void* d_ws, size_t ws_size,
                              hipStream_t stream) {
    const float* I_ext = (const float*)d_in[0];
    const float* V0    = (const float*)d_in[1];
    const float* w0    = (const float*)d_in[2];

    const int N = in_sizes[1];          // 1024
    const int T = out_size / (2 * N);   // 40000

    const int block = 64;
    const int grid  = (N / 2 + block - 1) / block;   // 8 blocks, 2 neurons/lane

    if (N == 1024) {
        adex_kernel<1024><<<grid, block, 0, stream>>>(
            I_ext, V0, w0,
            (const float*)d_in[3], (const float*)d_in[4], (const float*)d_in[5],
            (const float*)d_in[6], (const float*)d_in[7], (const float*)d_in[8],
            (const float*)d_in[9], (const float*)d_in[10], (const float*)d_in[11],
            (const float*)d_in[12], (float*)d_out, T, N);
    } else {
        adex_kernel<0><<<grid, block, 0, stream>>>(
            I_ext, V0, w0,
            (const float*)d_in[3], (const float*)d_in[4], (const float*)d_in[5],
            (const float*)d_in[6], (const float*)d_in[7], (const float*)d_in[8],
            (const float*)d_in[9], (const float*)d_in[10], (const float*)d_in[11],
            (const float*)d_in[12], (float*)d_out, T, N);
    }
}

// Round 6
// 3148.067 us; speedup vs baseline: 2.4380x; 2.4380x over previous
//
#include <hip/hip_runtime.h>

// AdEx Euler integration, fp32 port of the jax/numpy reference.
// Sequential scan over T=40000 steps; N=1024 neurons -> 16 waves on 16 CUs.
// Measured: wall tracks the per-step DEPENDENT CHAIN ~1:1 (R2: removing
// ~170 chain-cyc of IEEE-div sequences cut wall by exactly that).
//
// R1: batched uniform I_ext scalar loads, double-buffered    8217 -> 7055 us
// R2: IEEE divs -> fp64 reciprocal-mul (Markstein, bit-exact) 7055 -> 4193 us
// R3: burst-store output buffering (store-WAR stalls)         4193 -> 4007 us
// R4: 2 neurons/lane pairing -> REGRESSED (compiler dissolved buffers,
//     serialized chains; VGPR=36 proved arrays never lived in regs). Reverted.
// R5: collapse the exp-argument chain: ex = v_exp_f32((V-V_T)*c) with
//     c = fl32(log2e/delta_T) (f64-computed). Replaces [cvt,mul_f64,cvt] +
//     OCML expf (mul, v_exp, clamp fixups) ~60 chain-cyc with sub+mul+exp
//     ~24. NOT bit-exact: arg perturbed ~2 ulp -> absmax expected ~1e-3
//     (threshold 1.98e-3). arg*log2e in [-6,21]: no overflow/denorm, so
//     skipping OCML's range fixups is safe.

__device__ __forceinline__ float fdiv_via_f64(float x, double inv_y) {
    // Markstein: f64 multiply by correctly-rounded f64 reciprocal rounds
    // identically to IEEE f32 division for all normal inputs. Bit-exact.
    return (float)((double)x * inv_y);
}

__device__ __forceinline__ float exp2_raw(float u) {
    float r;
    asm("v_exp_f32 %0, %1" : "=v"(r) : "v"(u));   // r = 2^u, ~1 ulp
    return r;
}

__global__ void __launch_bounds__(64, 1) adex_kernel(
    const float* __restrict__ I_ext,
    const float* __restrict__ V0,
    const float* __restrict__ w0,
    const float* __restrict__ p_V_rest,
    const float* __restrict__ p_V_reset,
    const float* __restrict__ p_V_T,
    const float* __restrict__ p_V_thres,
    const float* __restrict__ p_delta_T,
    const float* __restrict__ p_R,
    const float* __restrict__ p_tau,
    const float* __restrict__ p_tau_w,
    const float* __restrict__ p_a,
    const float* __restrict__ p_b,
    float* __restrict__ out,
    int T, int N)
{
    // No FMA contraction: reference fp32 uses separate mul+add rounding.
#pragma clang fp contract(off)
    int n = blockIdx.x * blockDim.x + threadIdx.x;
    if (n >= N) n = N - 1;   // keep control flow uniform (scalar I loads)

    const float dt      = 5e-5f;
    const float V_rest  = *p_V_rest;
    const float V_reset = *p_V_reset;
    const float V_T     = *p_V_T;
    const float V_thres = *p_V_thres;
    const float delta_T = *p_delta_T;
    const float R       = *p_R;
    const float tau     = *p_tau;
    const float tau_w   = *p_tau_w;
    const float a       = *p_a;
    const float b       = *p_b;
    const float b_over_dt = b / dt;   // once, off-loop (bit-identical hoist)

    // Hoisted f64 reciprocals (bit-exact div replacement, stays on V/w chains).
    const double inv_tau     = 1.0 / (double)tau;
    const double inv_tau_w   = 1.0 / (double)tau_w;
    const double inv_dt      = 1.0 / (double)dt;
    // exp((V-V_T)/dT) = 2^((V-V_T) * log2(e)/dT): single f32 constant,
    // computed in f64 and rounded once.
    const float c_exp = (float)(1.4426950408889634 / (double)delta_T);

    float V = V0[n];
    float w = w0[n];

    float* outV = out + n;
    float* outW = out + (size_t)T * N + n;

    // One Euler step; emits pre-step state into register buffers
    // (distinct regs per j -> no store-WAR aliasing; see R3).
#define ADEX_STEP(j, RI_k)                                          \
    {                                                               \
        oV[j] = V;                                                  \
        ow[j] = w;                                                  \
        float t1   = V - V_rest;                                    \
        float ex   = exp2_raw((V - V_T) * c_exp);                   \
        float s    = (-t1) + (delta_T * ex);                        \
        s          = s - (R * w);                                   \
        s          = s + (RI_k);                                    \
        float dvdt = fdiv_via_f64(s, inv_tau);                      \
        float tw   = (a * t1) - w;                                  \
        float dwdt = fdiv_via_f64(tw, inv_tau_w);                   \
        bool  spike  = V > V_thres;                                 \
        float dvdt_s = fdiv_via_f64(V_reset - V, inv_dt);           \
        dvdt = spike ? dvdt_s : dvdt;                               \
        dwdt = spike ? (dwdt + b_over_dt) : dwdt;                   \
        V = V + (dt * dvdt);                                        \
        w = w + (dt * dwdt);                                        \
    }

    // Double-buffered uniform I batches (R*I precomputed, off-chain).
    // I_ext has T+5 elements; prefetch base clamped so max index <= T+4.
    float A[16], B[16];
    float oV[16], ow[16];
#pragma unroll
    for (int j = 0; j < 16; ++j) A[j] = R * I_ext[j];

    for (int kb = 0; kb < T; kb += 32) {
        // prefetch B = I[kb+16 .. kb+31]  (kb <= T-32 -> max idx T-1, ok)
#pragma unroll
        for (int j = 0; j < 16; ++j) B[j] = R * I_ext[kb + 16 + j];

#pragma unroll
        for (int j = 0; j < 16; ++j) ADEX_STEP(j, A[j]);
#pragma unroll
        for (int j = 0; j < 16; ++j) { outV[(size_t)j * N] = oV[j];
                                       outW[(size_t)j * N] = ow[j]; }
        outV += (size_t)16 * N;
        outW += (size_t)16 * N;

        // prefetch A = I[kb+32 .. kb+47], clamped (pb+15 <= T+4)
        {
            int pb = kb + 32;
            if (pb > T - 11) pb = T - 11;
#pragma unroll
            for (int j = 0; j < 16; ++j) A[j] = R * I_ext[pb + j];
        }

#pragma unroll
        for (int j = 0; j < 16; ++j) ADEX_STEP(j, B[j]);
#pragma unroll
        for (int j = 0; j < 16; ++j) { outV[(size_t)j * N] = oV[j];
                                       outW[(size_t)j * N] = ow[j]; }
        outV += (size_t)16 * N;
        outW += (size_t)16 * N;
    }
#undef ADEX_STEP
}

extern "C" void kernel_launch(void* const* d_in, const int* in_sizes, int n_in,
                              void* d_out, int out_size, void* d_ws, size_t ws_size,
                              hipStream_t stream) {
    const float* I_ext = (const float*)d_in[0];
    const float* V0    = (const float*)d_in[1];
    const float* w0    = (const float*)d_in[2];

    const int N = in_sizes[1];          // 1024
    const int T = out_size / (2 * N);   // 40000

    const int block = 64;
    const int grid  = (N + block - 1) / block;   // 16 blocks

    adex_kernel<<<grid, block, 0, stream>>>(
        I_ext, V0, w0,
        (const float*)d_in[3],  // V_rest
        (const float*)d_in[4],  // V_reset
        (const float*)d_in[5],  // V_T
        (const float*)d_in[6],  // V_thres
        (const float*)d_in[7],  // delta_T
        (const float*)d_in[8],  // R
        (const float*)d_in[9],  // tau
        (const float*)d_in[10], // tau_w
        (const float*)d_in[11], // a
        (const float*)d_in[12], // b
        (float*)d_out, T, N);
}

// Round 7
// 2521.020 us; speedup vs baseline: 3.0445x; 1.2487x over previous
//
#include <hip/hip_runtime.h>

// AdEx Euler integration, fp32 port of the jax/numpy reference.
// Sequential scan over T=40000 steps; N=1024 neurons -> 16 waves on 16 CUs.
// Measured: wall tracks the per-step DEPENDENT CHAIN ~1:1 (R2, R5).
// Measured: trajectory is bit-stable under ~ulp perturbations of the
// derivative terms (R5's exp rework left absmax EXACTLY unchanged).
//
// R1: batched uniform I_ext scalar loads, double-buffered    8217 -> 7055 us
// R2: IEEE divs -> fp64 reciprocal-mul (Markstein, bit-exact) 7055 -> 4193 us
// R3: burst-store output buffering                            4193 -> 4007 us
// R4: 2 neurons/lane pairing -> REGRESSED (serialized chains). Reverted.
// R5: exp chain -> raw v_exp_f32 with folded log2e/delta_T    4007 -> 2878 us
// R6: fold integration constants, all-f32 body:
//       V += s*(dt/tau)        replaces s/tau then dt*dvdt
//       w += tw*(dt/tau_w)     likewise
//       spike: V += (V_reset-V)        replaces dt*((V_reset-V)/dt)
//              w += tw*(dt/tau_w) + b  replaces dt*(dwdt + b/dt)
//     Each fold changes rounding by <=2 ulp of the INCREMENT (state error
//     ~1e-9/step) - the perturbation class R5 proved harmless. Removes all
//     three f64 round-trips (~6 V-chain deps, ~9 slow-issue instrs).

__device__ __forceinline__ float exp2_raw(float u) {
    float r;
    asm("v_exp_f32 %0, %1" : "=v"(r) : "v"(u));   // r = 2^u, ~1 ulp
    return r;
}

__global__ void __launch_bounds__(64, 1) adex_kernel(
    const float* __restrict__ I_ext,
    const float* __restrict__ V0,
    const float* __restrict__ w0,
    const float* __restrict__ p_V_rest,
    const float* __restrict__ p_V_reset,
    const float* __restrict__ p_V_T,
    const float* __restrict__ p_V_thres,
    const float* __restrict__ p_delta_T,
    const float* __restrict__ p_R,
    const float* __restrict__ p_tau,
    const float* __restrict__ p_tau_w,
    const float* __restrict__ p_a,
    const float* __restrict__ p_b,
    float* __restrict__ out,
    int T, int N)
{
    // No FMA contraction: reference fp32 uses separate mul+add rounding.
#pragma clang fp contract(off)
    int n = blockIdx.x * blockDim.x + threadIdx.x;
    if (n >= N) n = N - 1;   // keep control flow uniform (scalar I loads)

    const float dt      = 5e-5f;
    const float V_rest  = *p_V_rest;
    const float V_reset = *p_V_reset;
    const float V_T     = *p_V_T;
    const float V_thres = *p_V_thres;
    const float delta_T = *p_delta_T;
    const float R       = *p_R;
    const float tau     = *p_tau;
    const float tau_w   = *p_tau_w;
    const float a       = *p_a;
    const float b       = *p_b;

    // Folded constants, each computed in f64 and rounded once to f32.
    const float c_exp = (float)(1.4426950408889634 / (double)delta_T); // log2e/dT
    const float c_v   = (float)((double)dt / (double)tau);             // dt/tau
    const float c_w   = (float)((double)dt / (double)tau_w);           // dt/tau_w

    float V = V0[n];
    float w = w0[n];

    float* outV = out + n;
    float* outW = out + (size_t)T * N + n;

    // One Euler step; pre-step state goes to register buffers (burst-stored
    // per 16-batch to keep store-WAR reuse distance long; see R3).
#define ADEX_STEP(j, RI_k)                                          \
    {                                                               \
        oV[j] = V;                                                  \
        ow[j] = w;                                                  \
        float t1   = V - V_rest;                                    \
        float ex   = exp2_raw((V - V_T) * c_exp);                   \
        float s    = (-t1) + (delta_T * ex);                        \
        s          = s - (R * w);                                   \
        s          = s + (RI_k);                                    \
        float dV   = s * c_v;                                       \
        float tw   = (a * t1) - w;                                  \
        float dw   = tw * c_w;                                      \
        bool  spike = V > V_thres;                                  \
        dV = spike ? (V_reset - V) : dV;                            \
        dw = spike ? (dw + b) : dw;                                 \
        V = V + dV;                                                 \
        w = w + dw;                                                 \
    }

    // Double-buffered uniform I batches (R*I precomputed, off-chain).
    // I_ext has T+5 elements; prefetch base clamped so max index <= T+4.
    float A[16], B[16];
    float oV[16], ow[16];
#pragma unroll
    for (int j = 0; j < 16; ++j) A[j] = R * I_ext[j];

    for (int kb = 0; kb < T; kb += 32) {
        // prefetch B = I[kb+16 .. kb+31]  (kb <= T-32 -> max idx T-1, ok)
#pragma unroll
        for (int j = 0; j < 16; ++j) B[j] = R * I_ext[kb + 16 + j];

#pragma unroll
        for (int j = 0; j < 16; ++j) ADEX_STEP(j, A[j]);
#pragma unroll
        for (int j = 0; j < 16; ++j) { outV[(size_t)j * N] = oV[j];
                                       outW[(size_t)j * N] = ow[j]; }
        outV += (size_t)16 * N;
        outW += (size_t)16 * N;

        // prefetch A = I[kb+32 .. kb+47], clamped (pb+15 <= T+4)
        {
            int pb = kb + 32;
            if (pb > T - 11) pb = T - 11;
#pragma unroll
            for (int j = 0; j < 16; ++j) A[j] = R * I_ext[pb + j];
        }

#pragma unroll
        for (int j = 0; j < 16; ++j) ADEX_STEP(j, B[j]);
#pragma unroll
        for (int j = 0; j < 16; ++j) { outV[(size_t)j * N] = oV[j];
                                       outW[(size_t)j * N] = ow[j]; }
        outV += (size_t)16 * N;
        outW += (size_t)16 * N;
    }
#undef ADEX_STEP
}

extern "C" void kernel_launch(void* const* d_in, const int* in_sizes, int n_in,
                              void* d_out, int out_size, void* d_ws, size_t ws_size,
                              hipStream_t stream) {
    const float* I_ext = (const float*)d_in[0];
    const float* V0    = (const float*)d_in[1];
    const float* w0    = (const float*)d_in[2];

    const int N = in_sizes[1];          // 1024
    const int T = out_size / (2 * N);   // 40000

    const int block = 64;
    const int grid  = (N + block - 1) / block;   // 16 blocks

    adex_kernel<<<grid, block, 0, stream>>>(
        I_ext, V0, w0,
        (const float*)d_in[3],  // V_rest
        (const float*)d_in[4],  // V_reset
        (const float*)d_in[5],  // V_T
        (const float*)d_in[6],  // V_thres
        (const float*)d_in[7],  // delta_T
        (const float*)d_in[8],  // R
        (const float*)d_in[9],  // tau
        (const float*)d_in[10], // tau_w
        (const float*)d_in[11], // a
        (const float*)d_in[12], // b
        (float*)d_out, T, N);
}

// Round 8
// 2152.550 us; speedup vs baseline: 3.5656x; 1.1712x over previous
//
#include <hip/hip_runtime.h>

// AdEx Euler integration, fp32 port of the jax/numpy reference.
// Sequential scan over T=40000 steps; N=1024 neurons -> 16 waves on 16 CUs.
// Measured: wall tracks the per-step DEPENDENT CHAIN ~1:1 (R2, R5, R6).
// Measured: trajectory is bit-stable under increment-level (~1e-9 state)
// rounding perturbations (R5/R6/R7 all left absmax EXACTLY 4.882812e-04).
//
// R1: batched uniform I_ext scalar loads, double-buffered    8217 -> 7055 us
// R2: IEEE divs -> fp64 reciprocal-mul (Markstein, bit-exact) 7055 -> 4193 us
// R3: burst-store output buffering                            4193 -> 4007 us
// R4: 2 neurons/lane pairing -> REGRESSED (serialized). Reverted.
// R5: exp chain -> raw v_exp_f32, folded log2e/delta_T        4007 -> 2878 us
// R6: fold dt/tau, dt/tau_w, drop all f64 from the loop       2878 -> 2255 us
// R8 (this): V critical path 10 deps -> 6:
//     ex3 = 2^(fma(V-V_T, log2e/dT, log2(dT*dt/tau)))  (exp pre-scaled for
//           integration - kills 2 chain muls)
//     u   = fma(-R, w, RI - t1); Vp = fma(u, dt/tau, V)   (parallel w/ exp)
//     Vn  = Vp + ex3; spike ? V_reset : Vn                (direct reset sel)
//     w:  tw = fma(a,t1,-w); wn = fma(tw, dt/tau_w, w); +b on spike.
//     All reassociations perturb increments at ~1 ulp - the proven class.

__device__ __forceinline__ float exp2_raw(float u) {
    float r;
    asm("v_exp_f32 %0, %1" : "=v"(r) : "v"(u));   // r = 2^u, ~1 ulp
    return r;
}

__global__ void __launch_bounds__(64, 1) adex_kernel(
    const float* __restrict__ I_ext,
    const float* __restrict__ V0,
    const float* __restrict__ w0,
    const float* __restrict__ p_V_rest,
    const float* __restrict__ p_V_reset,
    const float* __restrict__ p_V_T,
    const float* __restrict__ p_V_thres,
    const float* __restrict__ p_delta_T,
    const float* __restrict__ p_R,
    const float* __restrict__ p_tau,
    const float* __restrict__ p_tau_w,
    const float* __restrict__ p_a,
    const float* __restrict__ p_b,
    float* __restrict__ out,
    int T, int N)
{
    // No implicit contraction; all FMAs are explicit and intentional.
#pragma clang fp contract(off)
    int n = blockIdx.x * blockDim.x + threadIdx.x;
    if (n >= N) n = N - 1;   // keep control flow uniform (scalar I loads)

    const float V_rest  = *p_V_rest;
    const float V_reset = *p_V_reset;
    const float V_T     = *p_V_T;
    const float V_thres = *p_V_thres;
    const float delta_T = *p_delta_T;
    const float R       = *p_R;
    const float tau     = *p_tau;
    const float tau_w   = *p_tau_w;
    const float a       = *p_a;
    const float b       = *p_b;
    const float dt      = 5e-5f;

    // Folded constants, computed in f64, rounded once to f32.
    const float c_exp = (float)(1.4426950408889634 / (double)delta_T);   // log2e/dT
    const float c_v   = (float)((double)dt / (double)tau);               // dt/tau
    const float c_w   = (float)((double)dt / (double)tau_w);             // dt/tau_w
    // log2(delta_T * dt / tau): exp term arrives pre-scaled for integration.
    const float c_off = (float)(log2((double)delta_T * (double)dt / (double)tau));
    const float nR    = -R;

    float V = V0[n];
    float w = w0[n];

    float* outV = out + n;
    float* outW = out + (size_t)T * N + n;

    // One Euler step; pre-step state into register buffers, burst-stored
    // per 16-batch (long store-WAR reuse distance; see R3).
#define ADEX_STEP(j, RI_k)                                          \
    {                                                               \
        oV[j] = V;                                                  \
        ow[j] = w;                                                  \
        float ex3 = exp2_raw(fmaf(V - V_T, c_exp, c_off));          \
        float t1  = V - V_rest;                                     \
        float u   = fmaf(nR, w, (RI_k) - t1);                       \
        float Vp  = fmaf(u, c_v, V);                                \
        float Vn  = Vp + ex3;                                       \
        float tw  = fmaf(a, t1, -w);                                \
        float wn  = fmaf(tw, c_w, w);                               \
        bool  spike = V > V_thres;                                  \
        Vn = spike ? V_reset : Vn;                                  \
        wn = spike ? (wn + b) : wn;                                 \
        V = Vn;                                                     \
        w = wn;                                                     \
    }

    // Double-buffered uniform I batches (R*I precomputed, off-chain).
    // I_ext has T+5 elements; prefetch base clamped so max index <= T+4.
    float A[16], B[16];
    float oV[16], ow[16];
#pragma unroll
    for (int j = 0; j < 16; ++j) A[j] = R * I_ext[j];

    for (int kb = 0; kb < T; kb += 32) {
        // prefetch B = I[kb+16 .. kb+31]  (kb <= T-32 -> max idx T-1, ok)
#pragma unroll
        for (int j = 0; j < 16; ++j) B[j] = R * I_ext[kb + 16 + j];

#pragma unroll
        for (int j = 0; j < 16; ++j) ADEX_STEP(j, A[j]);
#pragma unroll
        for (int j = 0; j < 16; ++j) { outV[(size_t)j * N] = oV[j];
                                       outW[(size_t)j * N] = ow[j]; }
        outV += (size_t)16 * N;
        outW += (size_t)16 * N;

        // prefetch A = I[kb+32 .. kb+47], clamped (pb+15 <= T+4)
        {
            int pb = kb + 32;
            if (pb > T - 11) pb = T - 11;
#pragma unroll
            for (int j = 0; j < 16; ++j) A[j] = R * I_ext[pb + j];
        }

#pragma unroll
        for (int j = 0; j < 16; ++j) ADEX_STEP(j, B[j]);
#pragma unroll
        for (int j = 0; j < 16; ++j) { outV[(size_t)j * N] = oV[j];
                                       outW[(size_t)j * N] = ow[j]; }
        outV += (size_t)16 * N;
        outW += (size_t)16 * N;
    }
#undef ADEX_STEP
}

extern "C" void kernel_launch(void* const* d_in, const int* in_sizes, int n_in,
                              void* d_out, int out_size, void* d_ws, size_t ws_size,
                              hipStream_t stream) {
    const float* I_ext = (const float*)d_in[0];
    const float* V0    = (const float*)d_in[1];
    const float* w0    = (const float*)d_in[2];

    const int N = in_sizes[1];          // 1024
    const int T = out_size / (2 * N);   // 40000

    const int block = 64;
    const int grid  = (N + block - 1) / block;   // 16 blocks

    adex_kernel<<<grid, block, 0, stream>>>(
        I_ext, V0, w0,
        (const float*)d_in[3],  // V_rest
        (const float*)d_in[4],  // V_reset
        (const float*)d_in[5],  // V_T
        (const float*)d_in[6],  // V_thres
        (const float*)d_in[7],  // delta_T
        (const float*)d_in[8],  // R
        (const float*)d_in[9],  // tau
        (const float*)d_in[10], // tau_w
        (const float*)d_in[11], // a
        (const float*)d_in[12], // b
        (float*)d_out, T, N);
}